// Round 1
// baseline (625.756 us; speedup 1.0000x reference)
//
#include <hip/hip_runtime.h>
#include <hip/hip_bf16.h>

// Problem constants (GraphSAGE 3-layer + pool + linear)
#define FH 128      // F_IN == H == 128
#define OUTD 256
#define KC 32       // GEMM k-chunk
#define A_STRIDE 72   // LDS stride for A tile [k][node], 64+8 pad (2-way conflict = free)
#define B_STRIDE 132  // LDS stride for B tile [k][o], 128+4 pad

// ---------------------------------------------------------------- histogram
__global__ void hist_kernel(const int* __restrict__ dst, int* __restrict__ cnt, int E) {
    int e = blockIdx.x * 256 + threadIdx.x;
    if (e < E) atomicAdd(&cnt[dst[e]], 1);
}

// ------------------------------------------------- exclusive scan (1 block)
__global__ void scan_kernel(const int* __restrict__ cnt, int* __restrict__ rp,
                            float* __restrict__ dinv, int n) {
    __shared__ int wsum[16];
    __shared__ int carry_s;
    int t = threadIdx.x, lane = t & 63, w = t >> 6;
    if (t == 0) carry_s = 0;
    __syncthreads();
    for (int base = 0; base < n; base += 1024) {
        int i = base + t;
        int v = (i < n) ? cnt[i] : 0;
        int x = v;
        #pragma unroll
        for (int off = 1; off < 64; off <<= 1) {
            int y = __shfl_up(x, off, 64);
            if (lane >= off) x += y;
        }
        if (lane == 63) wsum[w] = x;
        __syncthreads();
        int carry = carry_s;
        int woff = 0;
        #pragma unroll
        for (int q = 0; q < 16; ++q) woff += (q < w) ? wsum[q] : 0;
        if (i < n) {
            rp[i] = carry + woff + x - v;
            dinv[i] = 1.0f / (float)max(v, 1);
        }
        __syncthreads();
        if (t == 1023) {
            int tot = 0;
            #pragma unroll
            for (int q = 0; q < 16; ++q) tot += wsum[q];
            carry_s = carry + tot;
        }
        __syncthreads();
    }
    if (t == 0) rp[n] = carry_s;
}

// --------------------------------------------------------- CSR edge scatter
__global__ void scatter_kernel(const int* __restrict__ src, const int* __restrict__ dst,
                               const int* __restrict__ rp, int* __restrict__ cursor,
                               int* __restrict__ esrc, int E) {
    int e = blockIdx.x * 256 + threadIdx.x;
    if (e < E) {
        int d = dst[e];
        int pos = rp[d] + atomicAdd(&cursor[d], 1);
        esrc[pos] = src[e];
    }
}

// ------------------------------------------------------- graph range bounds
__global__ void graph_bounds_kernel(const int* __restrict__ batch, int* __restrict__ gstart,
                                    int n, int g) {
    int i = blockIdx.x * 256 + threadIdx.x;
    if (i >= n) return;
    int b = batch[i];
    int pb = (i == 0) ? -1 : batch[i - 1];
    for (int q = pb + 1; q <= b; ++q) gstart[q] = i;
    if (i == n - 1) {
        for (int q = b + 1; q <= g; ++q) gstart[q] = n;
    }
}

// --------------------------------------------------- mean aggregation (CSR)
// one wave per node; lane covers 2 features (float2)
__global__ void agg_kernel(const float* __restrict__ h, const int* __restrict__ rp,
                           const int* __restrict__ esrc, const float* __restrict__ dinv,
                           float* __restrict__ agg, int n_nodes) {
    int node = blockIdx.x * 4 + (threadIdx.x >> 6);
    if (node >= n_nodes) return;
    int lane = threadIdx.x & 63;
    int f = lane * 2;
    int s0 = rp[node], s1 = rp[node + 1];
    float ax = 0.f, ay = 0.f;
    for (int j = s0; j < s1; ++j) {
        int s = esrc[j];
        float2 v = *(const float2*)(h + (size_t)s * FH + f);
        ax += v.x; ay += v.y;
    }
    float di = dinv[node];
    float2 o; o.x = ax * di; o.y = ay * di;
    *(float2*)(agg + (size_t)node * FH + f) = o;
}

// ------------------------------------------------------------- SAGE GEMM
// C[n][o] = (relu?)( bias[o] + sum_k A1[n][k]*W1[o][k] + A2[n][k]*W2[o][k] )
// block: 256 threads, tile 64 nodes x 128 outputs; microtile 4 nodes x 8 outs
__global__ __launch_bounds__(256, 2)
void sage_gemm(const float* __restrict__ A1, const float* __restrict__ A2,
               const float* __restrict__ W1, const float* __restrict__ W2,
               const float* __restrict__ bias, float* __restrict__ C,
               int n_nodes, int do_relu) {
    __shared__ float Al[KC][A_STRIDE];
    __shared__ float Bl[KC][B_STRIDE];

    int tid = threadIdx.x;
    int tx = tid & 15;        // output group: o = tx*8 .. +7
    int ty = tid >> 4;        // node group:   n = ty*4 .. +3
    int tx8 = tx * 8, ty4 = ty * 4;
    int bn0 = blockIdx.x * 64;

    float acc[4][8];
    #pragma unroll
    for (int i = 0; i < 4; ++i)
        #pragma unroll
        for (int j = 0; j < 8; ++j) acc[i][j] = 0.f;

    const float* Ap[2] = {A1, A2};
    const float* Wp[2] = {W1, W2};

    #pragma unroll
    for (int p = 0; p < 2; ++p) {
        const float* Aptr = Ap[p];
        const float* Wptr = Wp[p];
        for (int kc = 0; kc < FH; kc += KC) {
            // ---- stage A tile (transposed: Al[k][node]) ----
            {
                int kk = (tid & 7) * 4;
                int nl = tid >> 3;  // 0..31
                #pragma unroll
                for (int r = 0; r < 2; ++r) {
                    int node = nl + r * 32;
                    int gn = bn0 + node;
                    float4 v = make_float4(0.f, 0.f, 0.f, 0.f);
                    if (gn < n_nodes)
                        v = *(const float4*)(Aptr + (size_t)gn * FH + kc + kk);
                    Al[kk + 0][node] = v.x;
                    Al[kk + 1][node] = v.y;
                    Al[kk + 2][node] = v.z;
                    Al[kk + 3][node] = v.w;
                }
            }
            // ---- stage B tile (transposed: Bl[k][o] = W[o][k]) ----
            {
                int o = tid & 127;
                int half = tid >> 7;
                #pragma unroll
                for (int q = 0; q < 4; ++q) {
                    int kk = half * 16 + q * 4;
                    float4 wv = *(const float4*)(Wptr + (size_t)o * FH + kc + kk);
                    Bl[kk + 0][o] = wv.x;
                    Bl[kk + 1][o] = wv.y;
                    Bl[kk + 2][o] = wv.z;
                    Bl[kk + 3][o] = wv.w;
                }
            }
            __syncthreads();
            // ---- compute ----
            #pragma unroll
            for (int k = 0; k < KC; ++k) {
                float4 av = *(const float4*)&Al[k][ty4];
                float4 b0 = *(const float4*)&Bl[k][tx8];
                float4 b1 = *(const float4*)&Bl[k][tx8 + 4];
                float as[4] = {av.x, av.y, av.z, av.w};
                float bs[8] = {b0.x, b0.y, b0.z, b0.w, b1.x, b1.y, b1.z, b1.w};
                #pragma unroll
                for (int i = 0; i < 4; ++i)
                    #pragma unroll
                    for (int j = 0; j < 8; ++j)
                        acc[i][j] = fmaf(as[i], bs[j], acc[i][j]);
            }
            __syncthreads();
        }
    }

    // ---- epilogue ----
    #pragma unroll
    for (int i = 0; i < 4; ++i) {
        int gn = bn0 + ty4 + i;
        if (gn < n_nodes) {
            float4 o0, o1;
            float v[8];
            #pragma unroll
            for (int j = 0; j < 8; ++j) {
                float t = acc[i][j] + bias[tx8 + j];
                if (do_relu) t = fmaxf(t, 0.f);
                v[j] = t;
            }
            o0.x = v[0]; o0.y = v[1]; o0.z = v[2]; o0.w = v[3];
            o1.x = v[4]; o1.y = v[5]; o1.z = v[6]; o1.w = v[7];
            float* cp = C + (size_t)gn * FH + tx8;
            *(float4*)(cp) = o0;
            *(float4*)(cp + 4) = o1;
        }
    }
}

// --------------------------------------------------------------- pooling
// block per graph (128 threads = feature); batch is sorted so ranges work
__global__ void pool_kernel(const float* __restrict__ h, const int* __restrict__ gstart,
                            float* __restrict__ pooled) {
    int g = blockIdx.x;
    int f = threadIdx.x;
    int s = gstart[g], e = gstart[g + 1];
    float mx = -INFINITY, sum = 0.f;
    for (int n = s; n < e; ++n) {
        float v = h[(size_t)n * FH + f];
        mx = fmaxf(mx, v);
        sum += v;
    }
    int c = e - s;
    if (c == 0) mx = 0.f;
    pooled[(size_t)g * (2 * FH) + f] = mx;
    pooled[(size_t)g * (2 * FH) + FH + f] = sum / (float)max(c, 1);
}

// ------------------------------------------------------------ final linear
__global__ void final_gemm(const float* __restrict__ pooled, const float* __restrict__ Wlin,
                           const float* __restrict__ blin, float* __restrict__ out) {
    __shared__ float pr[2 * FH];
    int g = blockIdx.x, o = threadIdx.x;  // 256 threads
    pr[o] = pooled[(size_t)g * (2 * FH) + o];
    __syncthreads();
    const float4* wr = (const float4*)(Wlin + (size_t)o * (2 * FH));
    float acc = 0.f;
    #pragma unroll
    for (int j = 0; j < (2 * FH) / 4; ++j) {
        float4 wv = wr[j];
        acc += wv.x * pr[j * 4 + 0] + wv.y * pr[j * 4 + 1] +
               wv.z * pr[j * 4 + 2] + wv.w * pr[j * 4 + 3];
    }
    out[(size_t)g * OUTD + o] = acc + blin[o];
}

extern "C" void kernel_launch(void* const* d_in, const int* in_sizes, int n_in,
                              void* d_out, int out_size, void* d_ws, size_t ws_size,
                              hipStream_t stream) {
    const float* x     = (const float*)d_in[0];
    const int*   ei    = (const int*)d_in[1];
    const int*   batch = (const int*)d_in[2];
    const float* W1l = (const float*)d_in[3];
    const float* b1  = (const float*)d_in[4];
    const float* W1r = (const float*)d_in[5];
    const float* W2l = (const float*)d_in[6];
    const float* b2  = (const float*)d_in[7];
    const float* W2r = (const float*)d_in[8];
    const float* W3l = (const float*)d_in[9];
    const float* b3  = (const float*)d_in[10];
    const float* W3r = (const float*)d_in[11];
    const float* Wlin = (const float*)d_in[12];
    const float* blin = (const float*)d_in[13];
    float* out = (float*)d_out;

    const int E = in_sizes[1] / 2;
    const int N = in_sizes[2];
    const int G = out_size / OUTD;
    const int* src = ei;
    const int* dst = ei + E;

    // ---- workspace carve-up ----
    char* w = (char*)d_ws;
    auto alloc = [&](size_t bytes) {
        void* p = (void*)w;
        w += (bytes + 255) & ~(size_t)255;
        return p;
    };
    int*   cnt    = (int*)alloc((size_t)2 * N * sizeof(int));  // [0..N): hist, [N..2N): cursor
    int*   cursor = cnt + N;
    int*   rp     = (int*)alloc((size_t)(N + 1) * sizeof(int));
    int*   esrc   = (int*)alloc((size_t)E * sizeof(int));
    int*   gstart = (int*)alloc((size_t)(G + 1) * sizeof(int));
    float* dinv   = (float*)alloc((size_t)N * sizeof(float));
    float* agg    = (float*)alloc((size_t)N * FH * sizeof(float));
    float* hA     = (float*)alloc((size_t)N * FH * sizeof(float));
    float* hB     = (float*)alloc((size_t)N * FH * sizeof(float));
    float* pooled = (float*)alloc((size_t)G * 2 * FH * sizeof(float));

    // ---- CSR build ----
    hipMemsetAsync(cnt, 0, (size_t)2 * N * sizeof(int), stream);
    hist_kernel<<<(E + 255) / 256, 256, 0, stream>>>(dst, cnt, E);
    scan_kernel<<<1, 1024, 0, stream>>>(cnt, rp, dinv, N);
    scatter_kernel<<<(E + 255) / 256, 256, 0, stream>>>(src, dst, rp, cursor, esrc, E);
    graph_bounds_kernel<<<(N + 255) / 256, 256, 0, stream>>>(batch, gstart, N, G);

    const int agg_grid  = (N + 3) / 4;
    const int gemm_grid = (N + 63) / 64;

    // ---- layer 1 ----
    agg_kernel<<<agg_grid, 256, 0, stream>>>(x, rp, esrc, dinv, agg, N);
    sage_gemm<<<gemm_grid, 256, 0, stream>>>(agg, x, W1l, W1r, b1, hA, N, 1);
    // ---- layer 2 ----
    agg_kernel<<<agg_grid, 256, 0, stream>>>(hA, rp, esrc, dinv, agg, N);
    sage_gemm<<<gemm_grid, 256, 0, stream>>>(agg, hA, W2l, W2r, b2, hB, N, 1);
    // ---- layer 3 ----
    agg_kernel<<<agg_grid, 256, 0, stream>>>(hB, rp, esrc, dinv, agg, N);
    sage_gemm<<<gemm_grid, 256, 0, stream>>>(agg, hB, W3l, W3r, b3, hA, N, 0);

    // ---- pool + head ----
    pool_kernel<<<G, FH, 0, stream>>>(hA, gstart, pooled);
    final_gemm<<<G, OUTD, 0, stream>>>(pooled, Wlin, blin, out);
}

// Round 2
// 516.641 us; speedup vs baseline: 1.2112x; 1.2112x over previous
//
#include <hip/hip_runtime.h>
#include <hip/hip_bf16.h>

// Problem constants (GraphSAGE 3-layer + pool + linear)
#define FH 128      // F_IN == H == 128
#define OUTD 256
#define KC 32       // GEMM k-chunk
#define A_STRIDE 72   // LDS stride for A tile [k][node], 64+8 pad
#define B_STRIDE 132  // LDS stride for B tile [k][o], 128+4 pad
#define SCHUNK 2048   // scan chunk per block (256 thr x 8 elem)

// ---------------------------------------------------------------- histogram
__global__ void hist_kernel(const int* __restrict__ dst, int* __restrict__ cnt, int E) {
    int e = blockIdx.x * 256 + threadIdx.x;
    if (e < E) atomicAdd(&cnt[dst[e]], 1);
}

// ---------------------------------------------- scan pass A: per-block sums
__global__ void scanA_kernel(const int* __restrict__ cnt, int* __restrict__ bsum, int n) {
    __shared__ int ws[4];
    int b = blockIdx.x, t = threadIdx.x;
    int base = b * SCHUNK + t * 8;
    int s = 0;
    #pragma unroll
    for (int k = 0; k < 8; ++k) {
        int i = base + k;
        s += (i < n) ? cnt[i] : 0;
    }
    #pragma unroll
    for (int off = 32; off >= 1; off >>= 1) s += __shfl_xor(s, off, 64);
    int w = t >> 6, lane = t & 63;
    if (lane == 0) ws[w] = s;
    __syncthreads();
    if (t == 0) bsum[b] = ws[0] + ws[1] + ws[2] + ws[3];
}

// ------------------------------- scan pass B: scan block sums (1 wave, B<=64)
__global__ void scanB_kernel(const int* __restrict__ bsum, int* __restrict__ boff,
                             int* __restrict__ rp, int B, int n) {
    int t = threadIdx.x;  // 64 threads
    int v = (t < B) ? bsum[t] : 0;
    int x = v;
    #pragma unroll
    for (int off = 1; off < 64; off <<= 1) {
        int y = __shfl_up(x, off, 64);
        if (t >= off) x += y;
    }
    if (t < B) boff[t] = x - v;
    if (t == 63) rp[n] = x;  // grand total == E
}

// --------------------------- scan pass C: full exclusive scan + emit rp/dinv
__global__ void scanC_kernel(const int* __restrict__ cnt, const int* __restrict__ boff,
                             int* __restrict__ rp, float* __restrict__ dinv, int n) {
    __shared__ int ws[4];
    int b = blockIdx.x, t = threadIdx.x;
    int base = b * SCHUNK + t * 8;
    int v[8];
    int ts = 0;
    #pragma unroll
    for (int k = 0; k < 8; ++k) {
        int i = base + k;
        v[k] = (i < n) ? cnt[i] : 0;
        ts += v[k];
    }
    int w = t >> 6, lane = t & 63;
    int x = ts;
    #pragma unroll
    for (int off = 1; off < 64; off <<= 1) {
        int y = __shfl_up(x, off, 64);
        if (lane >= off) x += y;
    }
    if (lane == 63) ws[w] = x;
    __syncthreads();
    int woff = 0;
    #pragma unroll
    for (int q = 0; q < 4; ++q) woff += (q < w) ? ws[q] : 0;
    int run = boff[b] + woff + (x - ts);
    #pragma unroll
    for (int k = 0; k < 8; ++k) {
        int i = base + k;
        if (i < n) {
            rp[i] = run;
            dinv[i] = 1.0f / (float)max(v[k], 1);
        }
        run += v[k];
    }
}

// --------------------------------------------------------- CSR edge scatter
__global__ void scatter_kernel(const int* __restrict__ src, const int* __restrict__ dst,
                               const int* __restrict__ rp, int* __restrict__ cursor,
                               int* __restrict__ esrc, int E) {
    int e = blockIdx.x * 256 + threadIdx.x;
    if (e < E) {
        int d = dst[e];
        int pos = rp[d] + atomicAdd(&cursor[d], 1);
        esrc[pos] = src[e];
    }
}

// ------------------------------------------------------- graph range bounds
__global__ void graph_bounds_kernel(const int* __restrict__ batch, int* __restrict__ gstart,
                                    int n, int g) {
    int i = blockIdx.x * 256 + threadIdx.x;
    if (i >= n) return;
    int b = batch[i];
    int pb = (i == 0) ? -1 : batch[i - 1];
    for (int q = pb + 1; q <= b; ++q) gstart[q] = i;
    if (i == n - 1) {
        for (int q = b + 1; q <= g; ++q) gstart[q] = n;
    }
}

// --------------------------------------------------- mean aggregation (CSR)
// half-wave (32 lanes) per node; lane covers 4 features (float4 = 512B/edge);
// edge loop unrolled x4 with independent accumulators -> 8 gathers in flight
// per wave (latency-bound fix: R1 showed VALUBusy 11%, HBM 27%)
__global__ void agg_kernel(const float* __restrict__ h, const int* __restrict__ rp,
                           const int* __restrict__ esrc, const float* __restrict__ dinv,
                           float* __restrict__ agg, int n_nodes) {
    int node = blockIdx.x * 8 + (threadIdx.x >> 5);
    if (node >= n_nodes) return;
    int lane = threadIdx.x & 31;
    int f = lane * 4;
    int s0 = rp[node], s1 = rp[node + 1];
    float4 a0 = make_float4(0.f, 0.f, 0.f, 0.f);
    float4 a1 = a0, a2 = a0, a3 = a0;
    int j = s0;
    for (; j + 4 <= s1; j += 4) {
        int i0 = esrc[j], i1 = esrc[j + 1], i2 = esrc[j + 2], i3 = esrc[j + 3];
        float4 v0 = *(const float4*)(h + (size_t)i0 * FH + f);
        float4 v1 = *(const float4*)(h + (size_t)i1 * FH + f);
        float4 v2 = *(const float4*)(h + (size_t)i2 * FH + f);
        float4 v3 = *(const float4*)(h + (size_t)i3 * FH + f);
        a0.x += v0.x; a0.y += v0.y; a0.z += v0.z; a0.w += v0.w;
        a1.x += v1.x; a1.y += v1.y; a1.z += v1.z; a1.w += v1.w;
        a2.x += v2.x; a2.y += v2.y; a2.z += v2.z; a2.w += v2.w;
        a3.x += v3.x; a3.y += v3.y; a3.z += v3.z; a3.w += v3.w;
    }
    if (j + 2 <= s1) {
        int i0 = esrc[j], i1 = esrc[j + 1];
        float4 v0 = *(const float4*)(h + (size_t)i0 * FH + f);
        float4 v1 = *(const float4*)(h + (size_t)i1 * FH + f);
        a0.x += v0.x; a0.y += v0.y; a0.z += v0.z; a0.w += v0.w;
        a1.x += v1.x; a1.y += v1.y; a1.z += v1.z; a1.w += v1.w;
        j += 2;
    }
    if (j < s1) {
        int i0 = esrc[j];
        float4 v0 = *(const float4*)(h + (size_t)i0 * FH + f);
        a2.x += v0.x; a2.y += v0.y; a2.z += v0.z; a2.w += v0.w;
    }
    float di = dinv[node];
    float4 o;
    o.x = (a0.x + a1.x + a2.x + a3.x) * di;
    o.y = (a0.y + a1.y + a2.y + a3.y) * di;
    o.z = (a0.z + a1.z + a2.z + a3.z) * di;
    o.w = (a0.w + a1.w + a2.w + a3.w) * di;
    *(float4*)(agg + (size_t)node * FH + f) = o;
}

// ------------------------------------------------------------- SAGE GEMM
// C[n][o] = (relu?)( bias[o] + sum_k A1[n][k]*W1[o][k] + A2[n][k]*W2[o][k] )
// block: 256 threads, tile 64 nodes x 128 outputs; microtile 4 nodes x 8 outs
__global__ __launch_bounds__(256, 2)
void sage_gemm(const float* __restrict__ A1, const float* __restrict__ A2,
               const float* __restrict__ W1, const float* __restrict__ W2,
               const float* __restrict__ bias, float* __restrict__ C,
               int n_nodes, int do_relu) {
    __shared__ float Al[KC][A_STRIDE];
    __shared__ float Bl[KC][B_STRIDE];

    int tid = threadIdx.x;
    int tx = tid & 15;        // output group: o = tx*8 .. +7
    int ty = tid >> 4;        // node group:   n = ty*4 .. +3
    int tx8 = tx * 8, ty4 = ty * 4;
    int bn0 = blockIdx.x * 64;

    float acc[4][8];
    #pragma unroll
    for (int i = 0; i < 4; ++i)
        #pragma unroll
        for (int j = 0; j < 8; ++j) acc[i][j] = 0.f;

    const float* Ap[2] = {A1, A2};
    const float* Wp[2] = {W1, W2};

    #pragma unroll
    for (int p = 0; p < 2; ++p) {
        const float* Aptr = Ap[p];
        const float* Wptr = Wp[p];
        for (int kc = 0; kc < FH; kc += KC) {
            // ---- stage A tile (transposed: Al[k][node]) ----
            {
                int kk = (tid & 7) * 4;
                int nl = tid >> 3;  // 0..31
                #pragma unroll
                for (int r = 0; r < 2; ++r) {
                    int node = nl + r * 32;
                    int gn = bn0 + node;
                    float4 v = make_float4(0.f, 0.f, 0.f, 0.f);
                    if (gn < n_nodes)
                        v = *(const float4*)(Aptr + (size_t)gn * FH + kc + kk);
                    Al[kk + 0][node] = v.x;
                    Al[kk + 1][node] = v.y;
                    Al[kk + 2][node] = v.z;
                    Al[kk + 3][node] = v.w;
                }
            }
            // ---- stage B tile (transposed: Bl[k][o] = W[o][k]) ----
            {
                int o = tid & 127;
                int half = tid >> 7;
                #pragma unroll
                for (int q = 0; q < 4; ++q) {
                    int kk = half * 16 + q * 4;
                    float4 wv = *(const float4*)(Wptr + (size_t)o * FH + kc + kk);
                    Bl[kk + 0][o] = wv.x;
                    Bl[kk + 1][o] = wv.y;
                    Bl[kk + 2][o] = wv.z;
                    Bl[kk + 3][o] = wv.w;
                }
            }
            __syncthreads();
            // ---- compute ----
            #pragma unroll
            for (int k = 0; k < KC; ++k) {
                float4 av = *(const float4*)&Al[k][ty4];
                float4 b0 = *(const float4*)&Bl[k][tx8];
                float4 b1 = *(const float4*)&Bl[k][tx8 + 4];
                float as[4] = {av.x, av.y, av.z, av.w};
                float bs[8] = {b0.x, b0.y, b0.z, b0.w, b1.x, b1.y, b1.z, b1.w};
                #pragma unroll
                for (int i = 0; i < 4; ++i)
                    #pragma unroll
                    for (int j = 0; j < 8; ++j)
                        acc[i][j] = fmaf(as[i], bs[j], acc[i][j]);
            }
            __syncthreads();
        }
    }

    // ---- epilogue ----
    #pragma unroll
    for (int i = 0; i < 4; ++i) {
        int gn = bn0 + ty4 + i;
        if (gn < n_nodes) {
            float4 o0, o1;
            float v[8];
            #pragma unroll
            for (int j = 0; j < 8; ++j) {
                float t = acc[i][j] + bias[tx8 + j];
                if (do_relu) t = fmaxf(t, 0.f);
                v[j] = t;
            }
            o0.x = v[0]; o0.y = v[1]; o0.z = v[2]; o0.w = v[3];
            o1.x = v[4]; o1.y = v[5]; o1.z = v[6]; o1.w = v[7];
            float* cp = C + (size_t)gn * FH + tx8;
            *(float4*)(cp) = o0;
            *(float4*)(cp + 4) = o1;
        }
    }
}

// --------------------------------------------------------------- pooling
__global__ void pool_kernel(const float* __restrict__ h, const int* __restrict__ gstart,
                            float* __restrict__ pooled) {
    int g = blockIdx.x;
    int f = threadIdx.x;
    int s = gstart[g], e = gstart[g + 1];
    float mx = -INFINITY, sum = 0.f;
    for (int n = s; n < e; ++n) {
        float v = h[(size_t)n * FH + f];
        mx = fmaxf(mx, v);
        sum += v;
    }
    int c = e - s;
    if (c == 0) mx = 0.f;
    pooled[(size_t)g * (2 * FH) + f] = mx;
    pooled[(size_t)g * (2 * FH) + FH + f] = sum / (float)max(c, 1);
}

// ------------------------------------------------------------ final linear
__global__ void final_gemm(const float* __restrict__ pooled, const float* __restrict__ Wlin,
                           const float* __restrict__ blin, float* __restrict__ out) {
    __shared__ float pr[2 * FH];
    int g = blockIdx.x, o = threadIdx.x;  // 256 threads
    pr[o] = pooled[(size_t)g * (2 * FH) + o];
    __syncthreads();
    const float4* wr = (const float4*)(Wlin + (size_t)o * (2 * FH));
    float acc = 0.f;
    #pragma unroll
    for (int j = 0; j < (2 * FH) / 4; ++j) {
        float4 wv = wr[j];
        acc += wv.x * pr[j * 4 + 0] + wv.y * pr[j * 4 + 1] +
               wv.z * pr[j * 4 + 2] + wv.w * pr[j * 4 + 3];
    }
    out[(size_t)g * OUTD + o] = acc + blin[o];
}

extern "C" void kernel_launch(void* const* d_in, const int* in_sizes, int n_in,
                              void* d_out, int out_size, void* d_ws, size_t ws_size,
                              hipStream_t stream) {
    const float* x     = (const float*)d_in[0];
    const int*   ei    = (const int*)d_in[1];
    const int*   batch = (const int*)d_in[2];
    const float* W1l = (const float*)d_in[3];
    const float* b1  = (const float*)d_in[4];
    const float* W1r = (const float*)d_in[5];
    const float* W2l = (const float*)d_in[6];
    const float* b2  = (const float*)d_in[7];
    const float* W2r = (const float*)d_in[8];
    const float* W3l = (const float*)d_in[9];
    const float* b3  = (const float*)d_in[10];
    const float* W3r = (const float*)d_in[11];
    const float* Wlin = (const float*)d_in[12];
    const float* blin = (const float*)d_in[13];
    float* out = (float*)d_out;

    const int E = in_sizes[1] / 2;
    const int N = in_sizes[2];
    const int G = out_size / OUTD;
    const int* src = ei;
    const int* dst = ei + E;
    const int NB = (N + SCHUNK - 1) / SCHUNK;  // scan blocks (<=64)

    // ---- workspace carve-up ----
    char* w = (char*)d_ws;
    auto alloc = [&](size_t bytes) {
        void* p = (void*)w;
        w += (bytes + 255) & ~(size_t)255;
        return p;
    };
    int*   cnt    = (int*)alloc((size_t)2 * N * sizeof(int));  // [0..N): hist, [N..2N): cursor
    int*   cursor = cnt + N;
    int*   rp     = (int*)alloc((size_t)(N + 1) * sizeof(int));
    int*   esrc   = (int*)alloc((size_t)E * sizeof(int));
    int*   gstart = (int*)alloc((size_t)(G + 1) * sizeof(int));
    float* dinv   = (float*)alloc((size_t)N * sizeof(float));
    int*   bsum   = (int*)alloc(64 * sizeof(int));
    int*   boff   = (int*)alloc(64 * sizeof(int));
    float* agg    = (float*)alloc((size_t)N * FH * sizeof(float));
    float* hA     = (float*)alloc((size_t)N * FH * sizeof(float));
    float* hB     = (float*)alloc((size_t)N * FH * sizeof(float));
    float* pooled = (float*)alloc((size_t)G * 2 * FH * sizeof(float));

    // ---- CSR build ----
    hipMemsetAsync(cnt, 0, (size_t)2 * N * sizeof(int), stream);
    hist_kernel<<<(E + 255) / 256, 256, 0, stream>>>(dst, cnt, E);
    scanA_kernel<<<NB, 256, 0, stream>>>(cnt, bsum, N);
    scanB_kernel<<<1, 64, 0, stream>>>(bsum, boff, rp, NB, N);
    scanC_kernel<<<NB, 256, 0, stream>>>(cnt, boff, rp, dinv, N);
    scatter_kernel<<<(E + 255) / 256, 256, 0, stream>>>(src, dst, rp, cursor, esrc, E);
    graph_bounds_kernel<<<(N + 255) / 256, 256, 0, stream>>>(batch, gstart, N, G);

    const int agg_grid  = (N + 7) / 8;
    const int gemm_grid = (N + 63) / 64;

    // ---- layer 1 ----
    agg_kernel<<<agg_grid, 256, 0, stream>>>(x, rp, esrc, dinv, agg, N);
    sage_gemm<<<gemm_grid, 256, 0, stream>>>(agg, x, W1l, W1r, b1, hA, N, 1);
    // ---- layer 2 ----
    agg_kernel<<<agg_grid, 256, 0, stream>>>(hA, rp, esrc, dinv, agg, N);
    sage_gemm<<<gemm_grid, 256, 0, stream>>>(agg, hA, W2l, W2r, b2, hB, N, 1);
    // ---- layer 3 ----
    agg_kernel<<<agg_grid, 256, 0, stream>>>(hB, rp, esrc, dinv, agg, N);
    sage_gemm<<<gemm_grid, 256, 0, stream>>>(agg, hB, W3l, W3r, b3, hA, N, 0);

    // ---- pool + head ----
    pool_kernel<<<G, FH, 0, stream>>>(hA, gstart, pooled);
    final_gemm<<<G, OUTD, 0, stream>>>(pooled, Wlin, blin, out);
}